// Round 9
// baseline (3557.138 us; speedup 1.0000x reference)
//
#include <hip/hip_runtime.h>
#include <hip/hip_bf16.h>

#define NL  3
#define NB  128
#define NT  256
#define NH  512
#define NH3 1536
#define NBH (NB*NH)      // 65536
#define NM  (NB*NT)      // 32768

typedef __bf16 bf16x8 __attribute__((ext_vector_type(8)));
typedef float  floatx4 __attribute__((ext_vector_type(4)));
typedef int    intx4  __attribute__((ext_vector_type(4)));
typedef __hip_bfloat16 bf16;
typedef unsigned long long u64;

__device__ __forceinline__ floatx4 mfma16(bf16x8 a, bf16x8 b, floatx4 c) {
  return __builtin_amdgcn_mfma_f32_16x16x32_bf16(a, b, c, 0, 0, 0);
}
__device__ __forceinline__ void gload16(const void* g, void* l) {
  __builtin_amdgcn_global_load_lds(
      (const __attribute__((address_space(1))) unsigned int*)g,
      (__attribute__((address_space(3))) unsigned int*)l, 16, 0, 0);
}
__device__ __forceinline__ float fsig(float x)  { return 1.0f / (1.0f + __expf(-x)); }
__device__ __forceinline__ float ftanh(float x) { return 2.0f / (1.0f + __expf(-2.0f*x)) - 1.0f; }
__device__ __forceinline__ float b2f(unsigned short u) {
  unsigned v = (unsigned)u << 16; float f; __builtin_memcpy(&f, &v, 4); return f;
}
__device__ __forceinline__ unsigned short f2b(float f) {
  bf16 h = __float2bfloat16(f); unsigned short u; __builtin_memcpy(&u, &h, 2); return u;
}
__device__ __forceinline__ u64 ald(const u64* p) {
  return __hip_atomic_load(p, __ATOMIC_RELAXED, __HIP_MEMORY_SCOPE_AGENT);
}
__device__ __forceinline__ void ast(u64* p, u64 v) {
  __hip_atomic_store(p, v, __ATOMIC_RELAXED, __HIP_MEMORY_SCOPE_AGENT);
}

// Batched poll of 4 slots (16B each) at 4 independent addresses; single waitcnt = 1 RT.
// sc1 loads proven (round 4) to observe ast (agent-scope) stores.
__device__ __forceinline__ void ld4x16(const void* p0, const void* p1,
                                       const void* p2, const void* p3,
                                       intx4& a, intx4& b, intx4& c, intx4& d) {
  asm volatile(
      "global_load_dwordx4 %0, %4, off sc1\n\t"
      "global_load_dwordx4 %1, %5, off sc1\n\t"
      "global_load_dwordx4 %2, %6, off sc1\n\t"
      "global_load_dwordx4 %3, %7, off sc1\n\t"
      "s_waitcnt vmcnt(0)"
      : "=&v"(a), "=&v"(b), "=&v"(c), "=&v"(d)
      : "v"(p0), "v"(p1), "v"(p2), "v"(p3)
      : "memory");
}

// ---------- transpose + cvt weights: fp32 [NL][NH][NH3] -> bf16 [NL][NH3][NH] ----------
__global__ void transpose_cvt_kernel(const float* __restrict__ in, bf16* __restrict__ out) {
  __shared__ float tile[32][33];
  int l = blockIdx.z;
  int n0 = blockIdx.x * 32, k0 = blockIdx.y * 32;
  const float* src = in + (size_t)l * NH * NH3;
  bf16* dst = out + (size_t)l * NH3 * NH;
  int tx = threadIdx.x, ty = threadIdx.y;    // 32 x 8
#pragma unroll
  for (int i = 0; i < 4; i++)
    tile[ty + 8*i][tx] = src[(size_t)(k0 + ty + 8*i) * NH3 + n0 + tx];
  __syncthreads();
#pragma unroll
  for (int i = 0; i < 4; i++)
    dst[(size_t)(n0 + ty + 8*i) * NH + k0 + tx] = __float2bfloat16(tile[tx][ty + 8*i]);
}

// ---------- elementwise fp32 -> bf16 (x input) ----------
__global__ void cvt_x_kernel(const float* __restrict__ in, bf16* __restrict__ out) {
  size_t i = (size_t)blockIdx.x * blockDim.x + threadIdx.x;
  float4 v = ((const float4*)in)[i];
  ushort4 pk;
  pk.x = f2b(v.x); pk.y = f2b(v.y); pk.z = f2b(v.z); pk.w = f2b(v.w);
  ((ushort4*)out)[i] = pk;
}

// ---------- xp GEMM (proven): C[m][n] = A[m]@Bt[n]^T + bias[n], bf16 out ----------
__global__ void __launch_bounds__(256, 2) gemm_xp_kernel(
    const bf16* __restrict__ A, const bf16* __restrict__ Bt,
    const float* __restrict__ bias, bf16* __restrict__ C, int a_mode)
{
  __shared__ char alds[16384];
  __shared__ char blds[16384];
  int tid = threadIdx.x;
  int lane = tid & 63, w = tid >> 6;
  int mblk = blockIdx.x, nblk = blockIdx.y;
  int wm = w >> 1, wn = w & 1;
  int klane = (lane >> 4) * 8;
  int r0 = 2*w*16 + (lane & 15);
  size_t arow0, arow1;
  if (a_mode == 0) {
    arow0 = ((size_t)r0 * NT + mblk) * NH;
    arow1 = ((size_t)(r0 + 16) * NT + mblk) * NH;
  } else {
    arow0 = (size_t)(mblk*128 + r0) * NH;
    arow1 = arow0 + (size_t)16 * NH;
  }
  size_t brow0 = (size_t)(nblk*128 + 2*w*16 + (lane & 15)) * NH;
  size_t brow1 = brow0 + (size_t)16 * NH;

  floatx4 acc[4][4];
#pragma unroll
  for (int i = 0; i < 4; i++)
#pragma unroll
    for (int j = 0; j < 4; j++) acc[i][j] = (floatx4){0.f, 0.f, 0.f, 0.f};

  for (int kk = 0; kk < 8; kk++) {
    int kb = kk*64 + klane;
#pragma unroll
    for (int kt = 0; kt < 2; kt++) {
      int kg = kb + kt*32;
      gload16(A  + arow0 + kg, alds + (kt*8 + 2*w    ) * 1024);
      gload16(A  + arow1 + kg, alds + (kt*8 + 2*w + 1) * 1024);
      gload16(Bt + brow0 + kg, blds + (kt*8 + 2*w    ) * 1024);
      gload16(Bt + brow1 + kg, blds + (kt*8 + 2*w + 1) * 1024);
    }
    __syncthreads();
#pragma unroll
    for (int kt = 0; kt < 2; kt++) {
      bf16x8 af[4], bfr[4];
#pragma unroll
      for (int i = 0; i < 4; i++) af[i]  = *(const bf16x8*)(alds + ((kt*8 + wm*4 + i)*64 + lane)*16);
#pragma unroll
      for (int j = 0; j < 4; j++) bfr[j] = *(const bf16x8*)(blds + ((kt*8 + wn*4 + j)*64 + lane)*16);
#pragma unroll
      for (int i = 0; i < 4; i++)
#pragma unroll
        for (int j = 0; j < 4; j++)
          acc[i][j] = mfma16(af[i], bfr[j], acc[i][j]);
    }
    __syncthreads();
  }
  int cl = lane & 15, rbase = (lane >> 4) * 4;
#pragma unroll
  for (int i = 0; i < 4; i++) {
    int gm = mblk*128 + wm*64 + i*16 + rbase;
#pragma unroll
    for (int j = 0; j < 4; j++) {
      int gn = nblk*128 + wn*64 + j*16 + cl;
      float bv = bias[gn];
#pragma unroll
      for (int r = 0; r < 4; r++)
        C[(size_t)(gm + r) * NH3 + gn] = __float2bfloat16(acc[i][j][r] + bv);
    }
  }
}

// =====================================================================================
// gru_scan, round 9: R7 kernel + REGISTER-CAP FIX (__launch_bounds__(512, 1)).
// Round-8 post-mortem: 1024-thr block (4 waves/SIMD) caps regs at 128 -> 384-reg wf
// spilled catastrophically -> timeout. Working backwards: R1-R7 ALL declared
// __launch_bounds__(512,2) (2 waves/EU = 16 waves/CU) -> 128-reg cap -> the 192-reg
// wf array was NEVER resident (VGPR_Count=128 every round). It spilled to scratch and
// was re-read ~384KB/block/step from L2 (~2.8us/step at per-CU L2 BW) -- which is why
// FOUR different exchange protocols all floored at ~4us/step: step time was
// max(weight-reload, exchange), reload dominating. The R1 launder was a no-op because
// residency was IMPOSSIBLE under the cap, not because the compiler declined.
// Fix: (512, 1) -> 8 waves/block = 2 waves/SIMD -> 256-reg budget; wf(192)+working(~60)
// fits; launder (retained) forces materialization. One block/CU guaranteed. Fast-poll
// budget 64->256 iters (consumers now arrive sooner than producers' first publish).
// Everything else BYTE-IDENTICAL to round 7 (passed, 3556us).
// Verification signal: VGPR_Count 128 -> ~240-256. If unchanged, cap theory is wrong
// -> next round: 256-thr blocks (1 wave/SIMD, 512-reg budget).
// =====================================================================================
__global__ void __launch_bounds__(512, 1) gru_scan_kernel(
    const bf16*  __restrict__ wuT,   // [NH3][NH] bf16 (this layer)
    const float* __restrict__ br,    // [NH3] recurrent bias
    const bf16*  __restrict__ xp,    // [NM][NH3] bf16, row = t*NB + b (bias folded)
    bf16*        __restrict__ seq,   // [NT+1][B][H] bf16; slot 256 on entry = prev layer h_255
    float*       __restrict__ hlast, // [B][H] fp32 carry handoff (in: prev layer, out: ours)
    float*       __restrict__ out,   // layer2: d_out; else null
    u64*         __restrict__ fbuf,  // [2 parity][8 grp][2048 slots] x 16B {d0,tag,d1,tag}
    unsigned tagbase, int layer)     // tagbase = layer*NT
{
  __shared__ __align__(16) char h_raw[2][16384];   // dbuf B-frags: [kt(16)][lane(64)]*16B
  __shared__ volatile int deadflag;
  int tid = threadIdx.x, lane = tid & 63, w = tid >> 6;   // 8 waves
  int g = blockIdx.x >> 2, c = blockIdx.x & 3;
  int bb0 = g * 16;
  int r16 = lane & 15, h4 = lane >> 4;
  int srow = tid & 15, ssc = tid >> 4;                    // staging (row, chunk-col)
  if (tid == 0) deadflag = 0;

  // ---- hoist weight A-fragments (loop-invariant): 3 x 16 x bf16x8 = 192 regs ----
  bf16x8 wf[3][16];
  float  bv[3][4];
#pragma unroll
  for (int G = 0; G < 3; G++) {
    const bf16* wrow = wuT + ((size_t)(G*NH + c*128 + w*16 + r16)) * NH + h4*8;
#pragma unroll
    for (int kt = 0; kt < 16; kt++) wf[G][kt] = *(const bf16x8*)(wrow + kt*32);
#pragma unroll
    for (int q = 0; q < 4; q++) bv[G][q] = br[G*NH + c*128 + w*16 + h4*4 + q];
  }
  // pin wf: with the 256-reg budget this now actually materializes registers
#pragma unroll
  for (int G = 0; G < 3; G++)
#pragma unroll
    for (int kt = 0; kt < 16; kt++) {
      floatx4 t = __builtin_bit_cast(floatx4, wf[G][kt]);
      asm volatile("" : "+v"(t));
      wf[G][kt] = __builtin_bit_cast(bf16x8, t);
    }

  // ---- fp32 carry: this lane's 4 h-elements ----
  float hreg[4];
  if (layer == 0) {
    hreg[0] = hreg[1] = hreg[2] = hreg[3] = 0.0f;
  } else {
    const float* hsrc = hlast + (size_t)(bb0 + r16) * NH + c*128 + w*16 + h4*4;
    float4 v = *(const float4*)hsrc;          // prev kernel's output: plain load OK
    hreg[0] = v.x; hreg[1] = v.y; hreg[2] = v.z; hreg[3] = v.w;
  }

  u64* seqU = (u64*)seq;
  const size_t PARU = (size_t)8 * 2048 * 2;    // u64 per parity (256KB)
  const size_t GRPU = (size_t)2048 * 2;        // u64 per group
  // producer slot pair: slotidx = c*512 + w*64 + lane
  size_t puboff = (size_t)g*GRPU + (size_t)(c*512 + w*64 + lane)*2;
  // consumer slot pairs: k*512 + w*64 + lane, k = 0..3 (chunk j = k*32 + ssc)
  size_t cbase  = (size_t)g*GRPU + (size_t)(w*64 + lane)*2;
  bool fastok = true;

  for (int t = 0; t < NT; t++) {
    // ---- stage h_prev [16x512] into B-fragment layout, buffer t&1 ----
    if (t == 0) {
      if (layer == 0) {
        *(int4*)(h_raw[0] + tid*32)      = (int4){0,0,0,0};
        *(int4*)(h_raw[0] + tid*32 + 16) = (int4){0,0,0,0};
      } else {   // prev layer's h_255 in seq slot 256 (previous dispatch)
        const u64* src = seqU + ((size_t)NT*NBH + (size_t)(bb0 + srow)*NH) / 4;
#pragma unroll
        for (int d = 0; d < 2; d++) {
          int sc = ssc + d*32;           // 16B chunk sc of row srow: k = sc*8..+8
          u64 q0 = ald(src + sc*2), q1 = ald(src + sc*2 + 1);
          u64* dst = (u64*)(h_raw[0] + (((sc >> 2)*64) + (sc & 3)*16 + srow)*16);
          dst[0] = q0; dst[1] = q1;
        }
      }
    } else {
      const u64* pb = fbuf + (size_t)(t & 1)*PARU + cbase;
      unsigned want = tagbase + (unsigned)t;
      int w_ = (int)want;
      u64 q0 = 0, q1 = 0, q2 = 0, q3 = 0;
      bool got = false;
      if (fastok) {                       // batched 1-RT poll, both sides coalesced
        const void* p0 = (const void*)(pb);
        const void* p1 = (const void*)(pb + 1024);   // +512 slots
        const void* p2 = (const void*)(pb + 2048);
        const void* p3 = (const void*)(pb + 3072);
        for (int it = 0; it < 256; ++it) {
          intx4 A, B2, C2, D2;
          ld4x16(p0, p1, p2, p3, A, B2, C2, D2);
          if (A.y == w_ && A.w == w_ && B2.y == w_ && B2.w == w_ &&
              C2.y == w_ && C2.w == w_ && D2.y == w_ && D2.w == w_) {
            q0 = (u64)(unsigned)A.x  | ((u64)(unsigned)A.z  << 32);
            q1 = (u64)(unsigned)B2.x | ((u64)(unsigned)B2.z << 32);
            q2 = (u64)(unsigned)C2.x | ((u64)(unsigned)C2.z << 32);
            q3 = (u64)(unsigned)D2.x | ((u64)(unsigned)D2.z << 32);
            got = true; break;
          }
        }
        if (!got) fastok = false;         // latch to proven path (same addresses)
      }
      if (!got) {                         // round-3-proven per-slot agent atomic loads
        int it = 0;
        while (!deadflag) {
          u64 a0 = ald(pb+0),    a1 = ald(pb+1);
          u64 b0 = ald(pb+1024), b1 = ald(pb+1025);
          u64 c0 = ald(pb+2048), c1 = ald(pb+2049);
          u64 d0 = ald(pb+3072), d1 = ald(pb+3073);
          bool ok = ((unsigned)(a0 >> 32) == want) & ((unsigned)(a1 >> 32) == want) &
                    ((unsigned)(b0 >> 32) == want) & ((unsigned)(b1 >> 32) == want) &
                    ((unsigned)(c0 >> 32) == want) & ((unsigned)(c1 >> 32) == want) &
                    ((unsigned)(d0 >> 32) == want) & ((unsigned)(d1 >> 32) == want);
          if (ok) {
            q0 = (u64)(unsigned)a0 | ((u64)(unsigned)a1 << 32);
            q1 = (u64)(unsigned)b0 | ((u64)(unsigned)b1 << 32);
            q2 = (u64)(unsigned)c0 | ((u64)(unsigned)c1 << 32);
            q3 = (u64)(unsigned)d0 | ((u64)(unsigned)d1 << 32);
            break;
          }
          if (++it > (1 << 17)) { deadflag = 1; break; }   // escalate: never hang
        }
      }
      // load k delivers chunk j = k*32 + ssc (h cols j*4..+4 of row srow)
      char* hb = h_raw[t & 1];
      int j0 = ssc, j1 = ssc + 32, j2 = ssc + 64, j3 = ssc + 96;
      *(u64*)(hb + (((j0>>3)*64 + ((j0>>1)&3)*16 + srow)*16 + (j0&1)*8)) = q0;
      *(u64*)(hb + (((j1>>3)*64 + ((j1>>1)&3)*16 + srow)*16 + (j1&1)*8)) = q1;
      *(u64*)(hb + (((j2>>3)*64 + ((j2>>1)&3)*16 + srow)*16 + (j2&1)*8)) = q2;
      *(u64*)(hb + (((j3>>3)*64 + ((j3>>1)&3)*16 + srow)*16 + (j3&1)*8)) = q3;
    }

    // xp_t prefetch (plain loads; written by an earlier dispatch) — hides under barrier/MFMA
    const u64* xq = (const u64*)(xp + ((size_t)t*NB + bb0 + r16)*NH3 + c*128 + w*16 + h4*4);
    u64 xv0 = xq[0], xv1 = xq[128], xv2 = xq[256];

    __syncthreads();                   // staging visible to all waves (only barrier/step)

    // ---- rec^T = Wu_cols x h : 3 tiles/wave, K=512, weights in registers ----
    const char* hbR = h_raw[t & 1];
    floatx4 ac0 = (floatx4){0,0,0,0}, ac1 = (floatx4){0,0,0,0}, ac2 = (floatx4){0,0,0,0};
#pragma unroll
    for (int kt = 0; kt < 16; kt++) {
      bf16x8 hb = *(const bf16x8*)(hbR + (kt*64 + lane)*16);
      ac0 = mfma16(wf[0][kt], hb, ac0);
      ac1 = mfma16(wf[1][kt], hb, ac1);
      ac2 = mfma16(wf[2][kt], hb, ac2);
    }

    // ---- gates in registers ----
    unsigned short pk[4];
#pragma unroll
    for (int q = 0; q < 4; q++) {
      float rz = ac0[q] + bv[0][q];
      float rr = ac1[q] + bv[1][q];
      float rh = ac2[q] + bv[2][q];
      float xz = b2f((unsigned short)(xv0 >> (16*q)));
      float xr = b2f((unsigned short)(xv1 >> (16*q)));
      float xh = b2f((unsigned short)(xv2 >> (16*q)));
      float z  = fsig(xz + rz);
      float r  = fsig(xr + rr);
      float hh = ftanh(xh + r * rh);
      float hn = z * hreg[q] + (1.0f - z) * hh;
      hreg[q] = hn;
      pk[q] = f2b(hn);
    }
    u64 pv; __builtin_memcpy(&pv, pk, 8);

    // ---- tagged publish: 2x 8B ast, wave-contiguous 1KB window (fire-and-forget) ----
    if (t < NT - 1) {
      u64 tg = (u64)(tagbase + (unsigned)t + 1u) << 32;
      u64* pp = fbuf + (size_t)((t + 1) & 1)*PARU + puboff;
      ast(pp,     ((u64)(unsigned)(pv & 0xffffffffu)) | tg);
      ast(pp + 1, ((u64)(unsigned)(pv >> 32))         | tg);
    }
    // seq slot t+1 for the next layer's GEMM (plain store; dispatch-boundary coherence)
    if (layer != 2)
      seqU[((size_t)(t+1)*NBH + (size_t)(bb0 + r16)*NH)/4 + c*32 + w*4 + h4] = pv;

    if (layer == 2) {                  // fp32 chain straight into d_out [B][T][H] flat
      float* o = out + ((size_t)(bb0 + r16)*NT + t)*NH + c*128 + w*16 + h4*4;
      *(float4*)o = (float4){hreg[0], hreg[1], hreg[2], hreg[3]};
      if (t == NT - 1) {               // final state tail [B][H]
        float* o2 = out + (size_t)NM*NH + (size_t)(bb0 + r16)*NH + c*128 + w*16 + h4*4;
        *(float4*)o2 = (float4){hreg[0], hreg[1], hreg[2], hreg[3]};
      }
    } else if (t == NT - 1) {          // fp32 carry handoff for next layer (plain store)
      float* o = hlast + (size_t)(bb0 + r16)*NH + c*128 + w*16 + h4*4;
      *(float4*)o = (float4){hreg[0], hreg[1], hreg[2], hreg[3]};
    }
    // no trailing barrier: LDS dbuf + (staging(t+2) transitively follows barrier(t+1))
  }
}

extern "C" void kernel_launch(void* const* d_in, const int* in_sizes, int n_in,
                              void* d_out, int out_size, void* d_ws, size_t ws_size,
                              hipStream_t stream) {
  const float* x   = (const float*)d_in[0];
  const float* wk  = (const float*)d_in[1];
  const float* wu  = (const float*)d_in[2];
  const float* bis = (const float*)d_in[3];
  float* out = (float*)d_out;

  // workspace layout:
  //   wkT   @ 0            4,718,592   [3][1536][512] bf16
  //   wuT   @ 4,718,592    4,718,592
  //   xp    @ 9,437,184  100,663,296   [32768][1536] bf16
  //   seq   @ 110,100,480 33,685,504   [257][128][512] bf16 (xb aliases base)
  //   hlast @ 143,785,984    262,144   [128][512] fp32
  //   fbuf  @ 144,048,128    524,288   [2][8][2048] x 16B tagged slots (doubly-coalesced)
  const size_t REQ = 144572416;
  if (ws_size < REQ) {
    hipMemsetAsync(d_out, 0, (size_t)out_size * 4, stream);
    return;
  }
  char* ws = (char*)d_ws;
  bf16*  wkT   = (bf16*)(ws);
  bf16*  wuT   = (bf16*)(ws + 4718592);
  bf16*  xp    = (bf16*)(ws + 9437184);
  bf16*  seq   = (bf16*)(ws + 110100480);
  bf16*  xb    = seq;                          // alias: dead after layer-0 GEMM
  float* hlast = (float*)(ws + 143785984);
  u64*   fbuf  = (u64*)(ws + 144048128);

  hipMemsetAsync(fbuf, 0, 524288, stream);     // zero tags: no cross-replay aliasing
  transpose_cvt_kernel<<<dim3(48,16,3), dim3(32,8), 0, stream>>>(wk, wkT);
  transpose_cvt_kernel<<<dim3(48,16,3), dim3(32,8), 0, stream>>>(wu, wuT);
  cvt_x_kernel<<<(NM*NH/4)/256, 256, 0, stream>>>(x, xb);

  const size_t WS = (size_t)NH3 * NH;   // per-layer weight stride

  // layer 0
  gemm_xp_kernel<<<dim3(256,12), 256, 0, stream>>>(xb, wkT, bis + 0*2*NH3, xp, 0);
  gru_scan_kernel<<<32, 512, 0, stream>>>(wuT, bis + 0*2*NH3 + NH3, xp,
      seq, hlast, nullptr, fbuf, 0u, 0);
  // layer 1 (gemm reads seq slots 1..256 = layer-0 h)
  gemm_xp_kernel<<<dim3(256,12), 256, 0, stream>>>(seq + NBH, wkT + WS, bis + 1*2*NH3, xp, 1);
  gru_scan_kernel<<<32, 512, 0, stream>>>(wuT + WS, bis + 1*2*NH3 + NH3, xp,
      seq, hlast, nullptr, fbuf, 256u, 1);
  // layer 2 (fp32 chain straight into d_out)
  gemm_xp_kernel<<<dim3(256,12), 256, 0, stream>>>(seq + NBH, wkT + 2*WS, bis + 2*2*NH3, xp, 1);
  gru_scan_kernel<<<32, 512, 0, stream>>>(wuT + 2*WS, bis + 2*2*NH3 + NH3, xp,
      seq, hlast, out, fbuf, 512u, 2);

  (void)in_sizes; (void)n_in; (void)out_size; (void)ws_size;
}